// Round 1
// baseline (533.319 us; speedup 1.0000x reference)
//
#include <hip/hip_runtime.h>
#include <stdint.h>
#include <math.h>

// ---------------------------------------------------------------------------
// MultiHeadAttention: B=4, S=2048, D=1024, H=16, dk=64
// q = (Q@WQ).reshape(B,16,2048,64)  (RAW reshape: head h = contiguous
//     131072-elt chunk of the [2048,1024] projected matrix, viewed [2048,64])
// scores = q k^T / 8 ; softmax ; ctx = attn @ v ; out = ctx_reassembled @ Wfc
// Strategy: bf16 MFMA everywhere (16x16x32), fp32 softmax in exp2 domain
// (0.125*log2e folded into Q projection epilogue scale).
// ---------------------------------------------------------------------------

typedef __attribute__((ext_vector_type(8))) short short8;
typedef __attribute__((ext_vector_type(4))) float f32x4;
typedef __attribute__((ext_vector_type(4))) unsigned int u32x4;

__device__ __forceinline__ unsigned short bf16rne(float f) {
  unsigned int u = __builtin_bit_cast(unsigned int, f);
  unsigned int r = u + 0x7FFFu + ((u >> 16) & 1u);
  return (unsigned short)(r >> 16);
}

// async global->LDS, 16B per lane. LDS dest must be wave-uniform base + lane*16.
__device__ __forceinline__ void gld_lds16(const void* g, void* l) {
  typedef __attribute__((address_space(3))) unsigned int lds_u32;
  typedef const __attribute__((address_space(1))) unsigned int glb_u32;
  __builtin_amdgcn_global_load_lds((glb_u32*)(uintptr_t)g,
                                   (lds_u32*)(unsigned int)(uintptr_t)l,
                                   16, 0, 0);
}

// ---------------------------------------------------------------------------
// fp32 -> bf16 convert for Q,K,V   (3 x 8192 x 1024)
// ---------------------------------------------------------------------------
__global__ void convert_x_kernel(const float* __restrict__ Q,
                                 const float* __restrict__ K,
                                 const float* __restrict__ V,
                                 unsigned short* __restrict__ Xb) {
  const int z = blockIdx.y;
  const float* src = (z == 0) ? Q : (z == 1) ? K : V;
  const size_t i0 = ((size_t)blockIdx.x * 256 + threadIdx.x) * 8;
  const f32x4 a = *(const f32x4*)(src + i0);
  const f32x4 c = *(const f32x4*)(src + i0 + 4);
  u32x4 o;
  o[0] = (unsigned)bf16rne(a[0]) | ((unsigned)bf16rne(a[1]) << 16);
  o[1] = (unsigned)bf16rne(a[2]) | ((unsigned)bf16rne(a[3]) << 16);
  o[2] = (unsigned)bf16rne(c[0]) | ((unsigned)bf16rne(c[1]) << 16);
  o[3] = (unsigned)bf16rne(c[2]) | ((unsigned)bf16rne(c[3]) << 16);
  *(u32x4*)(Xb + (size_t)z * 8388608 + i0) = o;
}

// ---------------------------------------------------------------------------
// W [K=1024][N=1024] fp32 -> Wt [N][K] bf16 (transposed so GEMMs are A*B^T)
// ---------------------------------------------------------------------------
__global__ void convert_w_kernel(const float* __restrict__ W0,
                                 const float* __restrict__ W1,
                                 const float* __restrict__ W2,
                                 const float* __restrict__ W3,
                                 unsigned short* __restrict__ Wt) {
  const int z = blockIdx.z;
  const float* W = (z == 0) ? W0 : (z == 1) ? W1 : (z == 2) ? W2 : W3;
  unsigned short* dst = Wt + (size_t)z * 1048576;
  __shared__ float tile[32][33];
  const int tx = threadIdx.x & 31, ty = threadIdx.x >> 5;
  const int k0 = blockIdx.x * 32, n0 = blockIdx.y * 32;
#pragma unroll
  for (int yy = 0; yy < 32; yy += 8)
    tile[ty + yy][tx] = W[(size_t)(k0 + ty + yy) * 1024 + n0 + tx];
  __syncthreads();
#pragma unroll
  for (int yy = 0; yy < 32; yy += 8)
    dst[(size_t)(n0 + ty + yy) * 1024 + k0 + tx] = bf16rne(tile[tx][ty + yy]);
}

// ---------------------------------------------------------------------------
// GEMM (m97 structure): C[z] = A[z][8192x1024] * Bt[z][1024x1024]^T
// 128x128 tile, BK=32, global_load_lds(16B), 4 waves in 2x2, 4x4 frags/wave.
// z==0 output scaled by scaleZ0 (Q projection: 0.125*log2e). Output bf16 if
// Cbf != nullptr else fp32 to Cf32.
// ---------------------------------------------------------------------------
__global__ __launch_bounds__(256, 2) void gemm_bt_kernel(
    const unsigned short* __restrict__ A, const unsigned short* __restrict__ Bt,
    unsigned short* __restrict__ Cbf, float* __restrict__ Cf32, float scaleZ0) {
  constexpr int K = 1024, N = 1024;
  const int z = blockIdx.z;
  const unsigned short* Ab = A + (size_t)z * 8192 * 1024;
  const unsigned short* Bb = Bt + (size_t)z * 1024 * 1024;
  const int tid = threadIdx.x;
  const int lane = tid & 63;
  const int w = tid >> 6;
  const int l15 = lane & 15, quad = lane >> 4;
  const int rowBase = blockIdx.x * 128;
  const int colBase = blockIdx.y * 128;
  const int wrow = (w >> 1) * 64;
  const int wcol = (w & 1) * 64;
  __shared__ __align__(16) unsigned short As[128 * 32];
  __shared__ __align__(16) unsigned short Bs[128 * 32];

  const f32x4 z4 = {0.0f, 0.0f, 0.0f, 0.0f};
  f32x4 acc[4][4];
#pragma unroll
  for (int i = 0; i < 4; i++)
#pragma unroll
    for (int j = 0; j < 4; j++) acc[i][j] = z4;

  const int s0 = tid, s1 = tid + 256;
  const int rA0 = s0 >> 2, cA0 = (s0 & 3) * 8;
  const int rA1 = s1 >> 2, cA1 = (s1 & 3) * 8;

  for (int k0 = 0; k0 < K; k0 += 32) {
    gld_lds16(Ab + (size_t)(rowBase + rA0) * K + k0 + cA0, (void*)(As + s0 * 8));
    gld_lds16(Ab + (size_t)(rowBase + rA1) * K + k0 + cA1, (void*)(As + s1 * 8));
    gld_lds16(Bb + (size_t)(colBase + rA0) * K + k0 + cA0, (void*)(Bs + s0 * 8));
    gld_lds16(Bb + (size_t)(colBase + rA1) * K + k0 + cA1, (void*)(Bs + s1 * 8));
    __syncthreads();
    short8 af[4], bfr[4];
#pragma unroll
    for (int i = 0; i < 4; i++)
      af[i] = *(const short8*)(As + (wrow + i * 16 + l15) * 32 + quad * 8);
#pragma unroll
    for (int j = 0; j < 4; j++)
      bfr[j] = *(const short8*)(Bs + (wcol + j * 16 + l15) * 32 + quad * 8);
#pragma unroll
    for (int i = 0; i < 4; i++)
#pragma unroll
      for (int j = 0; j < 4; j++)
        acc[i][j] =
            __builtin_amdgcn_mfma_f32_16x16x32_bf16(af[i], bfr[j], acc[i][j], 0, 0, 0);
    __syncthreads();
  }

  const float sc = (z == 0) ? scaleZ0 : 1.0f;
#pragma unroll
  for (int i = 0; i < 4; i++) {
#pragma unroll
    for (int j = 0; j < 4; j++) {
#pragma unroll
      for (int r = 0; r < 4; r++) {
        const int row = rowBase + wrow + i * 16 + quad * 4 + r;
        const int col = colBase + wcol + j * 16 + l15;
        const float v = acc[i][j][r] * sc;
        if (Cbf != nullptr) {
          Cbf[(size_t)z * 8192 * 1024 + (size_t)row * N + col] = bf16rne(v);
        } else {
          Cf32[(size_t)row * N + col] = v;
        }
      }
    }
  }
}

// ---------------------------------------------------------------------------
// Flash attention. Grid (16 q-tiles, 64 b*h). Block = 256 thr = 4 waves.
// Wave w owns q-rows [w*32, w*32+32) x full 128-key tile -> softmax wave-local.
// lin layout: [3][8192][1024] bf16; head (b,h) = contiguous chunk at
// (b*2048 + h*128)*1024, viewed [2048][64]. Q already scaled by 0.125*log2e.
// Output ctxr[b*2048 + s][h*64 + d] bf16.
// ---------------------------------------------------------------------------
__global__ __launch_bounds__(256, 2) void attn_kernel(
    const unsigned short* __restrict__ lin, unsigned short* __restrict__ ctxr) {
  const int qt = blockIdx.x;
  const int bh = blockIdx.y;
  const int b = bh >> 4, h = bh & 15;
  const int tid = threadIdx.x, lane = tid & 63, w = tid >> 6;
  const int l15 = lane & 15, quad = lane >> 4;
  const size_t headOff = (size_t)(b * 2048 + h * 128) * 1024;
  const unsigned short* qp = lin + headOff;
  const unsigned short* kp = lin + 8388608 + headOff;
  const unsigned short* vp = lin + 16777216 + headOff;

  // vt: [64][136] (V^T, padded; 16B-aligned rows). Pw: per-wave [32][136].
  __shared__ __align__(16) unsigned short lds[26112];
  unsigned short* vt = lds;
  unsigned short* Pw = lds + 8704 + w * 4352;

  // Q fragments (held in registers for the whole kernel)
  short8 aq[2][2];
  const int qrow0 = qt * 128 + w * 32;
#pragma unroll
  for (int i = 0; i < 2; i++)
#pragma unroll
    for (int kk = 0; kk < 2; kk++)
      aq[i][kk] =
          *(const short8*)(qp + (size_t)(qrow0 + i * 16 + l15) * 64 + kk * 32 + quad * 8);

  const f32x4 z4 = {0.0f, 0.0f, 0.0f, 0.0f};
  f32x4 co[2][4];
#pragma unroll
  for (int i = 0; i < 2; i++)
#pragma unroll
    for (int dj = 0; dj < 4; dj++) co[i][dj] = z4;
  float mrun[2][4], lrun[2][4];
#pragma unroll
  for (int i = 0; i < 2; i++)
#pragma unroll
    for (int r = 0; r < 4; r++) {
      mrun[i][r] = -INFINITY;
      lrun[i][r] = 0.0f;
    }

  for (int kt = 0; kt < 16; kt++) {
    __syncthreads();  // prior iteration's vt/P reads complete
    // ---- stage V^T into LDS: vt[d][key] = v[kt*128+key][d]
#pragma unroll
    for (int it = 0; it < 4; it++) {
      const int idx = it * 256 + tid;  // 0..1023
      const int key = idx >> 3, d0 = (idx & 7) * 8;
      const u32x4 vv = *(const u32x4*)(vp + (size_t)(kt * 128 + key) * 64 + d0);
#pragma unroll
      for (int m = 0; m < 4; m++) {
        vt[(d0 + 2 * m) * 136 + key] = (unsigned short)(vv[m] & 0xffffu);
        vt[(d0 + 2 * m + 1) * 136 + key] = (unsigned short)(vv[m] >> 16);
      }
    }
    // ---- S = q k^T (log2 domain; scale folded into q)
    f32x4 sacc[2][8];
#pragma unroll
    for (int j = 0; j < 8; j++) {
      const unsigned short* kb =
          kp + (size_t)(kt * 128 + j * 16 + l15) * 64 + quad * 8;
      const short8 bk0 = *(const short8*)(kb);
      const short8 bk1 = *(const short8*)(kb + 32);
#pragma unroll
      for (int i = 0; i < 2; i++) {
        f32x4 t = __builtin_amdgcn_mfma_f32_16x16x32_bf16(aq[i][0], bk0, z4, 0, 0, 0);
        sacc[i][j] = __builtin_amdgcn_mfma_f32_16x16x32_bf16(aq[i][1], bk1, t, 0, 0, 0);
      }
    }
    // ---- online softmax (rows live in 16-lane groups; shuffle-xor reduce)
    float alpha[2][4];
#pragma unroll
    for (int i = 0; i < 2; i++) {
#pragma unroll
      for (int r = 0; r < 4; r++) {
        float mx = sacc[i][0][r];
#pragma unroll
        for (int j = 1; j < 8; j++) mx = fmaxf(mx, sacc[i][j][r]);
#pragma unroll
        for (int msk = 1; msk < 16; msk <<= 1)
          mx = fmaxf(mx, __shfl_xor(mx, msk, 64));
        const float mnew = fmaxf(mrun[i][r], mx);
        const float a = exp2f(mrun[i][r] - mnew);
        float lsum = 0.0f;
#pragma unroll
        for (int j = 0; j < 8; j++) {
          const float p = exp2f(sacc[i][j][r] - mnew);
          sacc[i][j][r] = p;
          lsum += p;
        }
#pragma unroll
        for (int msk = 1; msk < 16; msk <<= 1) lsum += __shfl_xor(lsum, msk, 64);
        lrun[i][r] = lrun[i][r] * a + lsum;
        mrun[i][r] = mnew;
        alpha[i][r] = a;
      }
    }
#pragma unroll
    for (int i = 0; i < 2; i++)
#pragma unroll
      for (int dj = 0; dj < 4; dj++)
#pragma unroll
        for (int r = 0; r < 4; r++) co[i][dj][r] *= alpha[i][r];
    // ---- P (bf16) to per-wave LDS (C-layout -> A-layout round trip)
#pragma unroll
    for (int i = 0; i < 2; i++)
#pragma unroll
      for (int j = 0; j < 8; j++)
#pragma unroll
        for (int r = 0; r < 4; r++)
          Pw[(i * 16 + quad * 4 + r) * 136 + j * 16 + l15] = bf16rne(sacc[i][j][r]);
    __syncthreads();  // vt writes + P visible
    // ---- O += P @ V
    short8 ap[2][4];
#pragma unroll
    for (int i = 0; i < 2; i++)
#pragma unroll
      for (int kk = 0; kk < 4; kk++)
        ap[i][kk] = *(const short8*)(Pw + (i * 16 + l15) * 136 + kk * 32 + quad * 8);
#pragma unroll
    for (int dj = 0; dj < 4; dj++) {
      short8 bv[4];
#pragma unroll
      for (int kk = 0; kk < 4; kk++)
        bv[kk] = *(const short8*)(vt + (dj * 16 + l15) * 136 + kk * 32 + quad * 8);
#pragma unroll
      for (int i = 0; i < 2; i++)
#pragma unroll
        for (int kk = 0; kk < 4; kk++)
          co[i][dj] =
              __builtin_amdgcn_mfma_f32_16x16x32_bf16(ap[i][kk], bv[kk], co[i][dj], 0, 0, 0);
    }
  }

  // ---- epilogue: ctxr[b*2048 + s][h*64 + d] = co / l
#pragma unroll
  for (int i = 0; i < 2; i++) {
#pragma unroll
    for (int dj = 0; dj < 4; dj++) {
#pragma unroll
      for (int r = 0; r < 4; r++) {
        const int srow = qt * 128 + w * 32 + i * 16 + quad * 4 + r;
        const int col = h * 64 + dj * 16 + l15;
        const float v = co[i][dj][r] / lrun[i][r];
        ctxr[(size_t)(b * 2048 + srow) * 1024 + col] = bf16rne(v);
      }
    }
  }
}

// ---------------------------------------------------------------------------
extern "C" void kernel_launch(void* const* d_in, const int* in_sizes, int n_in,
                              void* d_out, int out_size, void* d_ws, size_t ws_size,
                              hipStream_t stream) {
  const float* Q = (const float*)d_in[0];
  const float* K = (const float*)d_in[1];
  const float* V = (const float*)d_in[2];
  const float* WQ = (const float*)d_in[3];
  const float* WK = (const float*)d_in[4];
  const float* WV = (const float*)d_in[5];
  const float* Wfc = (const float*)d_in[6];
  float* out = (float*)d_out;

  unsigned short* ws = (unsigned short*)d_ws;
  // ws layout (ushort units):
  //   Xb   @ 0         : 3*8388608 = 25165824   (bf16 Q,K,V)
  //   Wt   @ 25165824  : 4*1048576 = 4194304    (bf16 W^T: q,k,v,fc)
  //   lin  @ 29360128  : 3*8388608              (bf16 projections)
  //   ctxr @ 0 (reuse Xb; Xb dead after projections)
  // total = 109,051,904 bytes
  unsigned short* Xb = ws;
  unsigned short* Wt = ws + 25165824;
  unsigned short* lin = ws + 29360128;
  unsigned short* ctxr = ws;

  convert_x_kernel<<<dim3(4096, 3), 256, 0, stream>>>(Q, K, V, Xb);
  convert_w_kernel<<<dim3(32, 32, 4), 256, 0, stream>>>(WQ, WK, WV, Wfc, Wt);
  const float qscale = 0.125f * 1.4426950408889634f;  // 1/sqrt(dk) * log2(e)
  gemm_bt_kernel<<<dim3(64, 8, 3), 256, 0, stream>>>(Xb, Wt, lin, nullptr, qscale);
  attn_kernel<<<dim3(16, 64), 256, 0, stream>>>(lin, ctxr);
  gemm_bt_kernel<<<dim3(64, 8, 1), 256, 0, stream>>>(ctxr, Wt + 3 * 1048576, nullptr,
                                                     out, 1.0f);
}